// Round 1
// baseline (96.840 us; speedup 1.0000x reference)
//
#include <hip/hip_runtime.h>
#include <stdint.h>

// Problem constants (reference: B=8192, T=2048, L=256; binary fp32 vectors)
constexpr int T_ENTRIES = 2048;
constexpr int L_LEN     = 256;   // 256 bits = 4 x u64 per row

// One wave packs one 64-bit word of one table row via ballot.
// Output layout (SoA): packed[w * T_ENTRIES + t], w in [0,4).
__global__ void pack_keys_kernel(const float* __restrict__ keys,
                                 uint64_t* __restrict__ packed) {
    int gid  = blockIdx.x * blockDim.x + threadIdx.x;
    int wave = gid >> 6;
    int lane = gid & 63;
    int t = wave >> 2;       // table row
    int w = wave & 3;        // which 64-bit word of the row
    float v = keys[t * L_LEN + w * 64 + lane];   // coalesced: 64 consecutive floats
    uint64_t m = __ballot(v > 0.5f);             // bit[lane] = key bit
    if (lane == 0) packed[w * T_ENTRIES + t] = m;
}

// One wave per query. word0 of all keys in LDS (16 KB); words 1-3 verified
// from global (L2-hot, rare path) only on a word0 match.
__global__ __launch_bounds__(256) void match_kernel(
    const float* __restrict__ syndrome,
    const uint64_t* __restrict__ packed,
    const float* __restrict__ values,
    float* __restrict__ out,
    int B) {
    __shared__ uint64_t kw0[T_ENTRIES];
    int tid = threadIdx.x;
    for (int i = tid; i < T_ENTRIES; i += 256) kw0[i] = packed[i];
    __syncthreads();

    int lane    = tid & 63;
    int waveId  = blockIdx.x * (blockDim.x >> 6) + (tid >> 6);
    int nWaves  = gridDim.x * (blockDim.x >> 6);

    for (int q = waveId; q < B; q += nWaves) {
        const float* srow = syndrome + (size_t)q * L_LEN;
        // lane i reads elements i, i+64, i+128, i+192 -> 4 coalesced rounds;
        // each ballot directly yields one packed 64-bit word of the syndrome.
        uint64_t s0 = __ballot(srow[lane]       > 0.5f);
        uint64_t s1 = __ballot(srow[lane + 64]  > 0.5f);
        uint64_t s2 = __ballot(srow[lane + 128] > 0.5f);
        uint64_t s3 = __ballot(srow[lane + 192] > 0.5f);

        int best = T_ENTRIES;  // sentinel = miss
#pragma unroll
        for (int j = 0; j < T_ENTRIES / 64; ++j) {
            int t = lane + 64 * j;
            if (kw0[t] == s0) {                    // filters ~all misses
                if (packed[T_ENTRIES     + t] == s1 &&
                    packed[2 * T_ENTRIES + t] == s2 &&
                    packed[3 * T_ENTRIES + t] == s3) {
                    best = min(best, t);
                }
            }
        }
        // wave-wide min => first matching table index (argmax-of-mask semantics)
#pragma unroll
        for (int off = 32; off > 0; off >>= 1)
            best = min(best, __shfl_xor(best, off, 64));

        float4 o = make_float4(0.f, 0.f, 0.f, 0.f);   // miss -> zeros (d_out is poisoned)
        if (best < T_ENTRIES)
            o = ((const float4*)(values + (size_t)best * L_LEN))[lane];  // coalesced 1 KB row
        ((float4*)(out + (size_t)q * L_LEN))[lane] = o;
    }
}

extern "C" void kernel_launch(void* const* d_in, const int* in_sizes, int n_in,
                              void* d_out, int out_size, void* d_ws, size_t ws_size,
                              hipStream_t stream) {
    const float* syndrome = (const float*)d_in[0];
    const float* keys     = (const float*)d_in[1];
    const float* values   = (const float*)d_in[2];
    float* out = (float*)d_out;
    int B = in_sizes[0] / L_LEN;

    uint64_t* packed = (uint64_t*)d_ws;   // 8192 x u64 = 64 KB

    // 1 wave per packed word: T*4 waves = T*256 threads
    int packBlocks = (T_ENTRIES * 4 * 64) / 256;
    pack_keys_kernel<<<packBlocks, 256, 0, stream>>>(keys, packed);

    // 1 wave per query, 4 waves per block
    int nBlocks = (B + 3) / 4;
    match_kernel<<<nBlocks, 256, 0, stream>>>(syndrome, packed, values, out, B);
}

// Round 2
// 91.482 us; speedup vs baseline: 1.0586x; 1.0586x over previous
//
#include <hip/hip_runtime.h>
#include <stdint.h>

// B=8192 queries, T=2048 table rows, L=256 binary fp32 elements per row.
// Exact-match dict lookup: pack each 256-float binary row into 4 x u64 and
// compare bits. Bit permutation: word w, bit l  <->  element 4*l + w
// (from per-lane float4 loads + 4 ballots). Same permutation on both the
// table keys and the syndromes, so equality is preserved.
constexpr int T_ENTRIES = 2048;
constexpr int L_LEN     = 256;

// One wave per table row: 1 float4 load/lane + 4 ballots -> 4 packed words.
// SoA layout: packed[w * T_ENTRIES + t].
__global__ void pack_keys_kernel(const float* __restrict__ keys,
                                 uint64_t* __restrict__ packed) {
    int gid  = blockIdx.x * blockDim.x + threadIdx.x;
    int t    = gid >> 6;          // table row (one wave per row)
    int lane = gid & 63;
    float4 v = ((const float4*)(keys + (size_t)t * L_LEN))[lane];
    uint64_t w0 = __ballot(v.x > 0.5f);
    uint64_t w1 = __ballot(v.y > 0.5f);
    uint64_t w2 = __ballot(v.z > 0.5f);
    uint64_t w3 = __ballot(v.w > 0.5f);
    if (lane == 0) {
        packed[t]                 = w0;
        packed[T_ENTRIES     + t] = w1;
        packed[2 * T_ENTRIES + t] = w2;
        packed[3 * T_ENTRIES + t] = w3;
    }
}

// One wave per query. word0 of all keys staged in LDS (16 KB); words 1-3
// verified from global (L2-hot, rare path) only on a word0 match.
__global__ __launch_bounds__(256) void match_kernel(
    const float* __restrict__ syndrome,
    const uint64_t* __restrict__ packed,
    const float* __restrict__ values,
    float* __restrict__ out,
    int B) {
    __shared__ uint64_t kw0[T_ENTRIES];
    int tid = threadIdx.x;
    for (int i = tid; i < T_ENTRIES; i += 256) kw0[i] = packed[i];
    __syncthreads();

    int lane    = tid & 63;
    int waveId  = blockIdx.x * (blockDim.x >> 6) + (tid >> 6);
    int nWaves  = gridDim.x * (blockDim.x >> 6);

    for (int q = waveId; q < B; q += nWaves) {
        // Single dwordx4 load per lane; ballots give the 4 permuted words.
        float4 v = ((const float4*)(syndrome + (size_t)q * L_LEN))[lane];
        uint64_t s0 = __ballot(v.x > 0.5f);
        uint64_t s1 = __ballot(v.y > 0.5f);
        uint64_t s2 = __ballot(v.z > 0.5f);
        uint64_t s3 = __ballot(v.w > 0.5f);

        int best = T_ENTRIES;  // sentinel = miss
#pragma unroll
        for (int j = 0; j < T_ENTRIES / 64; ++j) {
            int t = lane + 64 * j;
            if (kw0[t] == s0) {                    // 64-bit filter kills ~all
                if (packed[T_ENTRIES     + t] == s1 &&
                    packed[2 * T_ENTRIES + t] == s2 &&
                    packed[3 * T_ENTRIES + t] == s3) {
                    best = min(best, t);
                }
            }
        }
        // wave-wide min => first matching table index (argmax-of-mask)
#pragma unroll
        for (int off = 32; off > 0; off >>= 1)
            best = min(best, __shfl_xor(best, off, 64));

        float4 o = make_float4(0.f, 0.f, 0.f, 0.f);   // miss -> zeros
        if (best < T_ENTRIES)
            o = ((const float4*)(values + (size_t)best * L_LEN))[lane];
        ((float4*)(out + (size_t)q * L_LEN))[lane] = o;
    }
}

extern "C" void kernel_launch(void* const* d_in, const int* in_sizes, int n_in,
                              void* d_out, int out_size, void* d_ws, size_t ws_size,
                              hipStream_t stream) {
    const float* syndrome = (const float*)d_in[0];
    const float* keys     = (const float*)d_in[1];
    const float* values   = (const float*)d_in[2];
    float* out = (float*)d_out;
    int B = in_sizes[0] / L_LEN;

    uint64_t* packed = (uint64_t*)d_ws;   // 4 * 2048 * 8 B = 64 KB

    // one wave per table row: T waves = T*64 threads
    int packBlocks = (T_ENTRIES * 64) / 256;
    pack_keys_kernel<<<packBlocks, 256, 0, stream>>>(keys, packed);

    // one wave per query, 4 waves per block (max occupancy: 8 blocks/CU)
    int nBlocks = (B + 3) / 4;
    match_kernel<<<nBlocks, 256, 0, stream>>>(syndrome, packed, values, out, B);
}